// Round 1
// baseline (1991.697 us; speedup 1.0000x reference)
//
#include <hip/hip_runtime.h>
#include <stdint.h>

typedef uint32_t u32;

#define NEGV (-1e9f)
#define MAXSEL 128

__device__ __forceinline__ u32 f2ord(float f) {
  u32 x = __float_as_uint(f);
  return (x & 0x80000000u) ? ~x : (x | 0x80000000u);
}
__device__ __forceinline__ float ord2f(u32 u) {
  u32 x = (u & 0x80000000u) ? (u ^ 0x80000000u) : ~u;
  return __uint_as_float(x);
}

// C[M x 512] = A[M x 512] @ W[512 x 512] + bias   (M = 4096 always here)
__global__ __launch_bounds__(256)
void gemm_bias(const float* __restrict__ A, const float* __restrict__ W,
               const float* __restrict__ bias, float* __restrict__ C) {
  __shared__ float As[16][68];  // [k][m], padded
  __shared__ float Bs[16][64];  // [k][n]
  const int tid = threadIdx.x;
  const int tx = tid & 15, ty = tid >> 4;
  const int n0 = blockIdx.x << 6, m0 = blockIdx.y << 6;
  float c[4][4] = {};
  for (int k0 = 0; k0 < 512; k0 += 16) {
    {
      const int row = tid >> 2, kp = (tid & 3) << 2;
      float4 av = *(const float4*)&A[(size_t)(m0 + row) * 512 + k0 + kp];
      As[kp + 0][row] = av.x;
      As[kp + 1][row] = av.y;
      As[kp + 2][row] = av.z;
      As[kp + 3][row] = av.w;
      const int kk = tid >> 4, np = (tid & 15) << 2;
      *(float4*)&Bs[kk][np] = *(const float4*)&W[(size_t)(k0 + kk) * 512 + n0 + np];
    }
    __syncthreads();
#pragma unroll
    for (int kk = 0; kk < 16; ++kk) {
      float4 a = *(const float4*)&As[kk][ty << 2];
      float4 b = *(const float4*)&Bs[kk][tx << 2];
      c[0][0] += a.x * b.x; c[0][1] += a.x * b.y; c[0][2] += a.x * b.z; c[0][3] += a.x * b.w;
      c[1][0] += a.y * b.x; c[1][1] += a.y * b.y; c[1][2] += a.y * b.z; c[1][3] += a.y * b.w;
      c[2][0] += a.z * b.x; c[2][1] += a.z * b.y; c[2][2] += a.z * b.z; c[2][3] += a.z * b.w;
      c[3][0] += a.w * b.x; c[3][1] += a.w * b.y; c[3][2] += a.w * b.z; c[3][3] += a.w * b.w;
    }
    __syncthreads();
  }
  float4 bv = *(const float4*)&bias[n0 + (tx << 2)];
#pragma unroll
  for (int i = 0; i < 4; ++i) {
    float4 o;
    o.x = c[i][0] + bv.x; o.y = c[i][1] + bv.y;
    o.z = c[i][2] + bv.z; o.w = c[i][3] + bv.w;
    *(float4*)&C[(size_t)(m0 + (ty << 2) + i) * 512 + n0 + (tx << 2)] = o;
  }
}

// scores[z][q][s] = 0.125 * dot64(q[b,q0+.,h,:], k[s0+.,h,:]) , masked -> exactly -1e9
__global__ __launch_bounds__(256)
void score_kernel(const float* __restrict__ qbuf, const float* __restrict__ kbuf,
                  const int* __restrict__ mask, float* __restrict__ sbuf, int sl0) {
  const int sl = sl0 + blockIdx.z;
  const int b = sl >> 3, h = sl & 7;
  const int s0 = blockIdx.x << 6, q0 = blockIdx.y << 6;
  __shared__ float Qs[64][68];
  __shared__ float Ks[64][68];
  const int tid = threadIdx.x;
  const float* qbase = qbuf + ((size_t)(b * 2048 + q0)) * 512 + h * 64;
  const float* kbase = kbuf + ((size_t)s0) * 512 + h * 64;
#pragma unroll
  for (int uu = 0; uu < 4; ++uu) {
    int p = tid + (uu << 8);
    int i = p >> 4, d = (p & 15) << 2;
    *(float4*)&Qs[i][d] = *(const float4*)&qbase[(size_t)i * 512 + d];
    *(float4*)&Ks[i][d] = *(const float4*)&kbase[(size_t)i * 512 + d];
  }
  __syncthreads();
  const int tx = tid & 15, ty = tid >> 4;
  float c[4][4] = {};
#pragma unroll
  for (int kk = 0; kk < 64; kk += 4) {
    float4 qa[4], kb[4];
#pragma unroll
    for (int i = 0; i < 4; ++i) qa[i] = *(const float4*)&Qs[(ty << 2) + i][kk];
#pragma unroll
    for (int j = 0; j < 4; ++j) kb[j] = *(const float4*)&Ks[(tx << 2) + j][kk];
#pragma unroll
    for (int i = 0; i < 4; ++i)
#pragma unroll
      for (int j = 0; j < 4; ++j)
        c[i][j] += qa[i].x * kb[j].x + qa[i].y * kb[j].y +
                   qa[i].z * kb[j].z + qa[i].w * kb[j].w;
  }
  float* srow = sbuf + ((size_t)blockIdx.z * 2048 + q0) * 4096 + s0;
  const int* mrow = mask + ((size_t)(b * 2048 + q0)) * 4096 + s0;
#pragma unroll
  for (int i = 0; i < 4; ++i) {
    int m = (ty << 2) + i;
    int4 mv = *(const int4*)&mrow[(size_t)m * 4096 + (tx << 2)];
    float4 o;
    o.x = mv.x ? c[i][0] * 0.125f : NEGV;
    o.y = mv.y ? c[i][1] * 0.125f : NEGV;
    o.z = mv.z ? c[i][2] * 0.125f : NEGV;
    o.w = mv.w ? c[i][3] * 0.125f : NEGV;
    *(float4*)&srow[(size_t)m * 4096 + (tx << 2)] = o;
  }
}

// one block per (slice, q-row): exact top-k threshold (radix select), softmax over
// survivors, sparse ctx = sum p_s * v[s,h,:]
__global__ __launch_bounds__(256)
void select_kernel(const float* __restrict__ sbuf, const float* __restrict__ vbuf,
                   float* __restrict__ ctxbuf, int sl0) {
  const int sl = sl0 + blockIdx.y;
  const int b = sl >> 3, h = sl & 7;
  const int qi = blockIdx.x;
  const int tid = threadIdx.x;
  __shared__ u32 hist[256];
  __shared__ u32 sscan[256];
  __shared__ float red[256];
  __shared__ int selIdx[MAXSEL];
  __shared__ float selE[MAXSEL];
  __shared__ u32 sh_dig, sh_krem;
  __shared__ int cnt;
  __shared__ float ssum, sh_m;

  const float* srow = sbuf + ((size_t)blockIdx.y * 2048 + qi) * 4096;
  const u32 ordneg = f2ord(NEGV);
  u32 u[16];
#pragma unroll
  for (int ch = 0; ch < 4; ++ch) {
    float4 v = *(const float4*)&srow[(ch << 10) + (tid << 2)];
    u[ch * 4 + 0] = f2ord(v.x);
    u[ch * 4 + 1] = f2ord(v.y);
    u[ch * 4 + 2] = f2ord(v.z);
    u[ch * 4 + 3] = f2ord(v.w);
  }
  // block max over ords
  u32 mymax = 0;
#pragma unroll
  for (int e = 0; e < 16; ++e) mymax = u[e] > mymax ? u[e] : mymax;
  sscan[tid] = mymax;
  __syncthreads();
  for (int off = 128; off > 0; off >>= 1) {
    if (tid < off) { u32 o = sscan[tid + off]; if (o > sscan[tid]) sscan[tid] = o; }
    __syncthreads();
  }
  if (tid == 0) { sh_m = ord2f(sscan[0]); cnt = 0; ssum = 0.f; }
  __syncthreads();
  const float fm = sh_m;

  // 4-pass radix select (MSB->LSB, 8-bit digits) for the exact 64th-largest value
  u32 prefix = 0, pm = 0;
  int kwant = 64;
  for (int pass = 0; pass < 4; ++pass) {
    const int shift = 24 - 8 * pass;
    hist[tid] = 0;
    __syncthreads();
#pragma unroll
    for (int e = 0; e < 16; ++e) {
      u32 ue = u[e];
      if (ue != ordneg && (ue & pm) == prefix) atomicAdd(&hist[(ue >> shift) & 255], 1u);
    }
    __syncthreads();
    sscan[tid] = hist[tid];
    __syncthreads();
    // suffix inclusive scan
    for (int off = 1; off < 256; off <<= 1) {
      u32 v = sscan[tid];
      u32 a = (tid + off < 256) ? sscan[tid + off] : 0u;
      __syncthreads();
      sscan[tid] = v + a;
      __syncthreads();
    }
    u32 inc = sscan[tid];
    u32 cex = inc - hist[tid];
    if (cex < (u32)kwant && (u32)kwant <= inc) { sh_dig = (u32)tid; sh_krem = (u32)kwant - cex; }
    __syncthreads();
    prefix |= sh_dig << shift;
    pm |= 0xFFu << shift;
    kwant = (int)sh_krem;
    __syncthreads();
  }
  const u32 thr = prefix;

  // collect survivors (score >= kth largest), exp in the same pass
#pragma unroll
  for (int ch = 0; ch < 4; ++ch) {
#pragma unroll
    for (int j = 0; j < 4; ++j) {
      u32 ue = u[ch * 4 + j];
      if (ue != ordneg && ue >= thr) {
        int p = atomicAdd(&cnt, 1);
        if (p < MAXSEL) {
          selIdx[p] = (ch << 10) + (tid << 2) + j;
          float e = __expf(ord2f(ue) - fm);
          selE[p] = e;
          atomicAdd(&ssum, e);
        }
      }
    }
  }
  __syncthreads();
  int nsel = cnt;
  if (nsel > MAXSEL) nsel = MAXSEL;
  const float rs = 1.0f / ssum;
  const int d = tid & 63, part = tid >> 6;
  float acc = 0.f;
  const float* vb = vbuf + h * 64 + d;
  for (int j = part; j < nsel; j += 4)
    acc += selE[j] * vb[(size_t)selIdx[j] * 512];
  red[tid] = acc;
  __syncthreads();
  if (tid < 64) {
    float tot = (red[d] + red[64 + d]) + (red[128 + d] + red[192 + d]);
    ctxbuf[((size_t)(b * 2048 + qi)) * 512 + h * 64 + d] = tot * rs;
  }
}

extern "C" void kernel_launch(void* const* d_in, const int* in_sizes, int n_in,
                              void* d_out, int out_size, void* d_ws, size_t ws_size,
                              hipStream_t stream) {
  const float* main_in = (const float*)d_in[0];
  const float* side_in = (const float*)d_in[1];
  const int*   mask    = (const int*)d_in[2];
  const float* Wq = (const float*)d_in[3];
  const float* bq = (const float*)d_in[4];
  const float* Wk = (const float*)d_in[5];
  const float* bk = (const float*)d_in[6];
  const float* Wv = (const float*)d_in[7];
  const float* bv = (const float*)d_in[8];
  const float* Wo = (const float*)d_in[9];
  const float* bo = (const float*)d_in[10];
  float* out = (float*)d_out;

  char* ws = (char*)d_ws;
  const size_t bufb = (size_t)4096 * 512 * 4;       // 8 MB per projection buffer
  float* qbuf   = (float*)(ws);
  float* kbuf   = (float*)(ws + bufb);
  float* vbuf   = (float*)(ws + 2 * bufb);
  float* ctxbuf = (float*)(ws + 3 * bufb);
  float* sbuf   = (float*)(ws + 4 * bufb);
  const size_t sliceb = (size_t)2048 * 4096 * 4;    // 32 MB per (b,h) score slice

  int nz = 1;
  if (ws_size > 4 * bufb + sliceb) {
    size_t m = (ws_size - 4 * bufb) / sliceb;
    nz = (int)(m > 16 ? 16 : m);
  }

  dim3 gblk(256);
  dim3 ggrid(512 / 64, 4096 / 64);
  gemm_bias<<<ggrid, gblk, 0, stream>>>(main_in, Wq, bq, qbuf);
  gemm_bias<<<ggrid, gblk, 0, stream>>>(side_in, Wk, bk, kbuf);
  gemm_bias<<<ggrid, gblk, 0, stream>>>(side_in, Wv, bv, vbuf);

  for (int sl0 = 0; sl0 < 16; sl0 += nz) {
    int z = nz < (16 - sl0) ? nz : (16 - sl0);
    score_kernel<<<dim3(64, 32, z), gblk, 0, stream>>>(qbuf, kbuf, mask, sbuf, sl0);
    select_kernel<<<dim3(2048, z), gblk, 0, stream>>>(sbuf, vbuf, ctxbuf, sl0);
  }

  gemm_bias<<<ggrid, gblk, 0, stream>>>(ctxbuf, Wo, bo, out);
}

// Round 2
// 1004.108 us; speedup vs baseline: 1.9835x; 1.9835x over previous
//
#include <hip/hip_runtime.h>
#include <stdint.h>

typedef uint32_t u32;
typedef unsigned long long u64;

#define NEGV (-1e9f)
#define MAXSEL 128

__device__ __forceinline__ u32 f2ord(float f) {
  u32 x = __float_as_uint(f);
  return (x & 0x80000000u) ? ~x : (x | 0x80000000u);
}
__device__ __forceinline__ float ord2f(u32 u) {
  u32 x = (u & 0x80000000u) ? (u ^ 0x80000000u) : ~u;
  return __uint_as_float(x);
}

// ---- mask packer: int32 mask [2][2048][4096] -> u64 bits [2][2048][64] ----
__global__ __launch_bounds__(256)
void pack_mask(const int* __restrict__ mask, u64* __restrict__ mbits) {
  int w = blockIdx.x * 256 + threadIdx.x;  // word id, 262144 total
  const int4* p = (const int4*)(mask + (size_t)w * 64);
  u64 bits = 0;
#pragma unroll
  for (int j = 0; j < 16; ++j) {
    int4 m = p[j];
    if (m.x) bits |= 1ull << (j * 4 + 0);
    if (m.y) bits |= 1ull << (j * 4 + 1);
    if (m.z) bits |= 1ull << (j * 4 + 2);
    if (m.w) bits |= 1ull << (j * 4 + 3);
  }
  mbits[w] = bits;
}

// ---- C[M x 512] = A[M x 512] @ W[512 x 512] + bias (row-major out) ----
__global__ __launch_bounds__(256)
void gemm_bias(const float* __restrict__ A, const float* __restrict__ W,
               const float* __restrict__ bias, float* __restrict__ C) {
  __shared__ float As[16][68];
  __shared__ float Bs[16][64];
  const int tid = threadIdx.x;
  const int tx = tid & 15, ty = tid >> 4;
  const int n0 = blockIdx.x << 6, m0 = blockIdx.y << 6;
  float c[4][4] = {};
  for (int k0 = 0; k0 < 512; k0 += 16) {
    {
      const int row = tid >> 2, kp = (tid & 3) << 2;
      float4 av = *(const float4*)&A[(size_t)(m0 + row) * 512 + k0 + kp];
      As[kp + 0][row] = av.x;
      As[kp + 1][row] = av.y;
      As[kp + 2][row] = av.z;
      As[kp + 3][row] = av.w;
      const int kk = tid >> 4, np = (tid & 15) << 2;
      *(float4*)&Bs[kk][np] = *(const float4*)&W[(size_t)(k0 + kk) * 512 + n0 + np];
    }
    __syncthreads();
#pragma unroll
    for (int kk = 0; kk < 16; ++kk) {
      float4 a = *(const float4*)&As[kk][ty << 2];
      float4 b = *(const float4*)&Bs[kk][tx << 2];
      c[0][0] += a.x * b.x; c[0][1] += a.x * b.y; c[0][2] += a.x * b.z; c[0][3] += a.x * b.w;
      c[1][0] += a.y * b.x; c[1][1] += a.y * b.y; c[1][2] += a.y * b.z; c[1][3] += a.y * b.w;
      c[2][0] += a.z * b.x; c[2][1] += a.z * b.y; c[2][2] += a.z * b.z; c[2][3] += a.z * b.w;
      c[3][0] += a.w * b.x; c[3][1] += a.w * b.y; c[3][2] += a.w * b.z; c[3][3] += a.w * b.w;
    }
    __syncthreads();
  }
  float4 bv = *(const float4*)&bias[n0 + (tx << 2)];
#pragma unroll
  for (int i = 0; i < 4; ++i) {
    float4 o;
    o.x = c[i][0] + bv.x; o.y = c[i][1] + bv.y;
    o.z = c[i][2] + bv.z; o.w = c[i][3] + bv.w;
    *(float4*)&C[(size_t)(m0 + (ty << 2) + i) * 512 + n0 + (tx << 2)] = o;
  }
}

// ---- same GEMM math, but stores k-major transposed:
//  qsh=11: CT[((b*8+h)*64+d)*2048 + q]   (rows m = b*2048+q)
//  qsh=12: CT[(h*64+d)*4096 + s]         (rows m = s)
__global__ __launch_bounds__(256)
void gemm_bias_T(const float* __restrict__ A, const float* __restrict__ W,
                 const float* __restrict__ bias, float* __restrict__ CT, int qsh) {
  __shared__ float As[16][68];
  __shared__ float Bs[16][64];
  const int tid = threadIdx.x;
  const int tx = tid & 15, ty = tid >> 4;
  const int n0 = blockIdx.x << 6, m0 = blockIdx.y << 6;
  float c[4][4] = {};
  for (int k0 = 0; k0 < 512; k0 += 16) {
    {
      const int row = tid >> 2, kp = (tid & 3) << 2;
      float4 av = *(const float4*)&A[(size_t)(m0 + row) * 512 + k0 + kp];
      As[kp + 0][row] = av.x;
      As[kp + 1][row] = av.y;
      As[kp + 2][row] = av.z;
      As[kp + 3][row] = av.w;
      const int kk = tid >> 4, np = (tid & 15) << 2;
      *(float4*)&Bs[kk][np] = *(const float4*)&W[(size_t)(k0 + kk) * 512 + n0 + np];
    }
    __syncthreads();
#pragma unroll
    for (int kk = 0; kk < 16; ++kk) {
      float4 a = *(const float4*)&As[kk][ty << 2];
      float4 b = *(const float4*)&Bs[kk][tx << 2];
      c[0][0] += a.x * b.x; c[0][1] += a.x * b.y; c[0][2] += a.x * b.z; c[0][3] += a.x * b.w;
      c[1][0] += a.y * b.x; c[1][1] += a.y * b.y; c[1][2] += a.y * b.z; c[1][3] += a.y * b.w;
      c[2][0] += a.z * b.x; c[2][1] += a.z * b.y; c[2][2] += a.z * b.z; c[2][3] += a.z * b.w;
      c[3][0] += a.w * b.x; c[3][1] += a.w * b.y; c[3][2] += a.w * b.z; c[3][3] += a.w * b.w;
    }
    __syncthreads();
  }
  float4 bv = *(const float4*)&bias[n0 + (tx << 2)];
  float bvv[4] = {bv.x, bv.y, bv.z, bv.w};
  const int qlen = 1 << qsh;
  const int qmask = qlen - 1;
#pragma unroll
  for (int i = 0; i < 4; ++i) {
#pragma unroll
    for (int j = 0; j < 4; ++j) {
      float val = c[i][j] + bvv[j];
      int m = m0 + (ty << 2) + i;
      int n = n0 + (tx << 2) + j;
      int h = n >> 6, d = n & 63;
      int bb = m >> qsh, q = m & qmask;
      CT[(((size_t)bb * 8 + h) * 64 + d) * qlen + q] = val;
    }
  }
}

// ---- scores: 128(q) x 128(s) tile per block, 8x8 micro, k-major LDS ----
__global__ __launch_bounds__(256)
void score_kernel(const float* __restrict__ qT, const float* __restrict__ kT,
                  const u64* __restrict__ mbits, float* __restrict__ sbuf, int sl0) {
  __shared__ float Qs[64][128];
  __shared__ float Ks[64][128];
  const int sl = sl0 + blockIdx.z;
  const int b = sl >> 3, h = sl & 7;
  const int s0 = blockIdx.x << 7, q0 = blockIdx.y << 7;
  const int tid = threadIdx.x;
  const float* qbase = qT + (size_t)sl * 64 * 2048 + q0;
  const float* kbase = kT + (size_t)h * 64 * 4096 + s0;
  float4* Qf = (float4*)&Qs[0][0];
  float4* Kf = (float4*)&Ks[0][0];
#pragma unroll
  for (int u = 0; u < 8; ++u) {
    int i = (u << 8) + tid;              // f4 index 0..2047
    int row = i >> 5, col = (i & 31) << 2;
    Qf[i] = *(const float4*)(qbase + (size_t)row * 2048 + col);
    Kf[i] = *(const float4*)(kbase + (size_t)row * 4096 + col);
  }
  __syncthreads();
  const int tx = tid & 15, ty = tid >> 4;
  float c[8][8] = {};
#pragma unroll 4
  for (int g = 0; g < 16; ++g) {
    const int kk = g << 2;
    float qa[8][4], kb[8][4];
#pragma unroll
    for (int t = 0; t < 4; ++t) {
#pragma unroll
      for (int i = 0; i < 8; ++i) qa[i][t] = Qs[kk + t][(ty << 3) + i];
#pragma unroll
      for (int j = 0; j < 4; ++j) {
        kb[j][t]     = Ks[kk + t][(tx << 2) + j];
        kb[4 + j][t] = Ks[kk + t][64 + (tx << 2) + j];
      }
    }
#pragma unroll
    for (int i = 0; i < 8; ++i)
#pragma unroll
      for (int j = 0; j < 8; ++j)
        c[i][j] += qa[i][0] * kb[j][0] + qa[i][1] * kb[j][1]
                 + qa[i][2] * kb[j][2] + qa[i][3] * kb[j][3];
  }
  float* srow = sbuf + ((size_t)blockIdx.z * 2048 + q0) * 4096 + s0;
  const u64* mrow = mbits + ((size_t)(b * 2048 + q0)) * 64 + (s0 >> 6);
#pragma unroll
  for (int i = 0; i < 8; ++i) {
    const int row = (ty << 3) + i;
    u64 wA = mrow[(size_t)row * 64];
    u64 wB = mrow[(size_t)row * 64 + 1];
    float4 o0, o1;
    o0.x = ((wA >> ((tx << 2) + 0)) & 1) ? c[i][0] * 0.125f : NEGV;
    o0.y = ((wA >> ((tx << 2) + 1)) & 1) ? c[i][1] * 0.125f : NEGV;
    o0.z = ((wA >> ((tx << 2) + 2)) & 1) ? c[i][2] * 0.125f : NEGV;
    o0.w = ((wA >> ((tx << 2) + 3)) & 1) ? c[i][3] * 0.125f : NEGV;
    o1.x = ((wB >> ((tx << 2) + 0)) & 1) ? c[i][4] * 0.125f : NEGV;
    o1.y = ((wB >> ((tx << 2) + 1)) & 1) ? c[i][5] * 0.125f : NEGV;
    o1.z = ((wB >> ((tx << 2) + 2)) & 1) ? c[i][6] * 0.125f : NEGV;
    o1.w = ((wB >> ((tx << 2) + 3)) & 1) ? c[i][7] * 0.125f : NEGV;
    *(float4*)&srow[(size_t)row * 4096 + (tx << 2)] = o0;
    *(float4*)&srow[(size_t)row * 4096 + 64 + (tx << 2)] = o1;
  }
}

// ---- select: one wave per q-row, no __syncthreads ----
__global__ __launch_bounds__(256)
void select_kernel(const float* __restrict__ sbuf, const float* __restrict__ vbuf,
                   float* __restrict__ ctxbuf, int sl0) {
  const int sl = sl0 + blockIdx.y;
  const int b = sl >> 3, h = sl & 7;
  const int wave = threadIdx.x >> 6, lane = threadIdx.x & 63;
  const int qi = (blockIdx.x << 2) + wave;
  __shared__ int s_idx[4][MAXSEL];
  __shared__ float s_e[4][MAXSEL];
  __shared__ int s_cnt[4];
  if (lane == 0) s_cnt[wave] = 0;
  const float* srow = sbuf + ((size_t)blockIdx.y * 2048 + qi) * 4096;
  u32 u[64];
#pragma unroll
  for (int j = 0; j < 16; ++j) {
    float4 v = *(const float4*)(srow + (j << 8) + (lane << 2));
    u[j * 4 + 0] = f2ord(v.x);
    u[j * 4 + 1] = f2ord(v.y);
    u[j * 4 + 2] = f2ord(v.z);
    u[j * 4 + 3] = f2ord(v.w);
  }
  // wave max
  u32 mx = 0;
#pragma unroll
  for (int e = 0; e < 64; ++e) mx = u[e] > mx ? u[e] : mx;
#pragma unroll
  for (int off = 32; off; off >>= 1) {
    u32 o = (u32)__shfl_xor((int)mx, off, 64);
    mx = o > mx ? o : mx;
  }
  const float fm = ord2f(mx);
  const u32 ordneg = f2ord(NEGV);
  // binary search for exact 64th-largest ord value
  u32 lo = ordneg, hi = mx + 1;
  while (hi - lo > 1) {
    u32 mid = lo + ((hi - lo) >> 1);
    int cnt = 0;
#pragma unroll
    for (int e = 0; e < 64; ++e)
      cnt += __popcll(__ballot(u[e] >= mid));
    if (cnt >= 64) lo = mid; else hi = mid;
  }
  const u32 thr = lo;
  // survivors -> wave-local LDS list (+ exp)
  float esum = 0.f;
#pragma unroll
  for (int e = 0; e < 64; ++e) {
    u32 ue = u[e];
    if (ue >= thr && ue != ordneg) {
      int p = atomicAdd(&s_cnt[wave], 1);
      if (p < MAXSEL) {
        int sidx = ((e >> 2) << 8) + (lane << 2) + (e & 3);
        float ev = __expf(ord2f(ue) - fm);
        s_idx[wave][p] = sidx;
        s_e[wave][p] = ev;
        esum += ev;
      }
    }
  }
#pragma unroll
  for (int off = 32; off; off >>= 1) esum += __shfl_xor(esum, off, 64);
  int nsel = s_cnt[wave];
  if (nsel > MAXSEL) nsel = MAXSEL;
  const float rs = 1.0f / esum;
  float acc = 0.f;
  const float* vb = vbuf + h * 64 + lane;
#pragma unroll 4
  for (int j = 0; j < nsel; ++j)
    acc += s_e[wave][j] * vb[(size_t)s_idx[wave][j] << 9];
  ctxbuf[((size_t)(b * 2048 + qi)) * 512 + h * 64 + lane] = acc * rs;
}

extern "C" void kernel_launch(void* const* d_in, const int* in_sizes, int n_in,
                              void* d_out, int out_size, void* d_ws, size_t ws_size,
                              hipStream_t stream) {
  const float* main_in = (const float*)d_in[0];
  const float* side_in = (const float*)d_in[1];
  const int*   mask    = (const int*)d_in[2];
  const float* Wq = (const float*)d_in[3];
  const float* bq = (const float*)d_in[4];
  const float* Wk = (const float*)d_in[5];
  const float* bk = (const float*)d_in[6];
  const float* Wv = (const float*)d_in[7];
  const float* bv = (const float*)d_in[8];
  const float* Wo = (const float*)d_in[9];
  const float* bo = (const float*)d_in[10];
  float* out = (float*)d_out;

  char* ws = (char*)d_ws;
  float* qT   = (float*)(ws);                       // 8 MB  [16][64][2048]
  float* kT   = (float*)(ws + ((size_t)8 << 20));   // 8 MB  [8][64][4096]
  float* vbuf = (float*)(ws + ((size_t)16 << 20));  // 8 MB  [4096][512]
  float* ctxb = (float*)(ws + ((size_t)24 << 20));  // 8 MB  [4096][512]
  u64* mbits  = (u64*)(ws + ((size_t)32 << 20));    // 2 MB  [2][2048][64]
  float* sbuf = (float*)(ws + ((size_t)34 << 20));  // nz * 32 MB
  const size_t base = (size_t)34 << 20;
  const size_t sliceb = (size_t)2048 * 4096 * 4;

  int nz = 1;
  if (ws_size > base + sliceb) {
    size_t m = (ws_size - base) / sliceb;
    nz = (int)(m > 16 ? 16 : m);
  }

  pack_mask<<<1024, 256, 0, stream>>>(mask, mbits);
  gemm_bias_T<<<dim3(8, 64), 256, 0, stream>>>(main_in, Wq, bq, qT, 11);
  gemm_bias_T<<<dim3(8, 64), 256, 0, stream>>>(side_in, Wk, bk, kT, 12);
  gemm_bias  <<<dim3(8, 64), 256, 0, stream>>>(side_in, Wv, bv, vbuf);

  for (int sl0 = 0; sl0 < 16; sl0 += nz) {
    int z = nz < (16 - sl0) ? nz : (16 - sl0);
    score_kernel <<<dim3(32, 16, z), 256, 0, stream>>>(qT, kT, mbits, sbuf, sl0);
    select_kernel<<<dim3(512, z), 256, 0, stream>>>(sbuf, vbuf, ctxb, sl0);
  }

  gemm_bias<<<dim3(8, 64), 256, 0, stream>>>(ctxb, Wo, bo, out);
}

// Round 3
// 824.632 us; speedup vs baseline: 2.4153x; 1.2176x over previous
//
#include <hip/hip_runtime.h>
#include <stdint.h>

typedef uint32_t u32;
typedef unsigned long long u64;

#define NEGV (-1e9f)
#define MAXSEL 128
#define NCAND 12

__device__ __forceinline__ u32 f2ord(float f) {
  u32 x = __float_as_uint(f);
  return (x & 0x80000000u) ? ~x : (x | 0x80000000u);
}
__device__ __forceinline__ float ord2f(u32 u) {
  u32 x = (u & 0x80000000u) ? (u ^ 0x80000000u) : ~u;
  return __uint_as_float(x);
}

// ---- mask packer: int32 mask [2][2048][4096] -> u64 bits [2][2048][64] ----
__global__ __launch_bounds__(256)
void pack_mask(const int* __restrict__ mask, u64* __restrict__ mbits) {
  int w = blockIdx.x * 256 + threadIdx.x;  // word id, 262144 total
  const int4* p = (const int4*)(mask + (size_t)w * 64);
  u64 bits = 0;
#pragma unroll
  for (int j = 0; j < 16; ++j) {
    int4 m = p[j];
    if (m.x) bits |= 1ull << (j * 4 + 0);
    if (m.y) bits |= 1ull << (j * 4 + 1);
    if (m.z) bits |= 1ull << (j * 4 + 2);
    if (m.w) bits |= 1ull << (j * 4 + 3);
  }
  mbits[w] = bits;
}

// ---- C[M x 512] = A[M x 512] @ W[512 x 512] + bias (row-major out) ----
__global__ __launch_bounds__(256)
void gemm_bias(const float* __restrict__ A, const float* __restrict__ W,
               const float* __restrict__ bias, float* __restrict__ C) {
  __shared__ float As[16][68];
  __shared__ float Bs[16][64];
  const int tid = threadIdx.x;
  const int tx = tid & 15, ty = tid >> 4;
  const int n0 = blockIdx.x << 6, m0 = blockIdx.y << 6;
  float c[4][4] = {};
  for (int k0 = 0; k0 < 512; k0 += 16) {
    {
      const int row = tid >> 2, kp = (tid & 3) << 2;
      float4 av = *(const float4*)&A[(size_t)(m0 + row) * 512 + k0 + kp];
      As[kp + 0][row] = av.x;
      As[kp + 1][row] = av.y;
      As[kp + 2][row] = av.z;
      As[kp + 3][row] = av.w;
      const int kk = tid >> 4, np = (tid & 15) << 2;
      *(float4*)&Bs[kk][np] = *(const float4*)&W[(size_t)(k0 + kk) * 512 + n0 + np];
    }
    __syncthreads();
#pragma unroll
    for (int kk = 0; kk < 16; ++kk) {
      float4 a = *(const float4*)&As[kk][ty << 2];
      float4 b = *(const float4*)&Bs[kk][tx << 2];
      c[0][0] += a.x * b.x; c[0][1] += a.x * b.y; c[0][2] += a.x * b.z; c[0][3] += a.x * b.w;
      c[1][0] += a.y * b.x; c[1][1] += a.y * b.y; c[1][2] += a.y * b.z; c[1][3] += a.y * b.w;
      c[2][0] += a.z * b.x; c[2][1] += a.z * b.y; c[2][2] += a.z * b.z; c[2][3] += a.z * b.w;
      c[3][0] += a.w * b.x; c[3][1] += a.w * b.y; c[3][2] += a.w * b.z; c[3][3] += a.w * b.w;
    }
    __syncthreads();
  }
  float4 bv = *(const float4*)&bias[n0 + (tx << 2)];
#pragma unroll
  for (int i = 0; i < 4; ++i) {
    float4 o;
    o.x = c[i][0] + bv.x; o.y = c[i][1] + bv.y;
    o.z = c[i][2] + bv.z; o.w = c[i][3] + bv.w;
    *(float4*)&C[(size_t)(m0 + (ty << 2) + i) * 512 + n0 + (tx << 2)] = o;
  }
}

// ---- same GEMM math, but stores k-major transposed ----
__global__ __launch_bounds__(256)
void gemm_bias_T(const float* __restrict__ A, const float* __restrict__ W,
                 const float* __restrict__ bias, float* __restrict__ CT, int qsh) {
  __shared__ float As[16][68];
  __shared__ float Bs[16][64];
  const int tid = threadIdx.x;
  const int tx = tid & 15, ty = tid >> 4;
  const int n0 = blockIdx.x << 6, m0 = blockIdx.y << 6;
  float c[4][4] = {};
  for (int k0 = 0; k0 < 512; k0 += 16) {
    {
      const int row = tid >> 2, kp = (tid & 3) << 2;
      float4 av = *(const float4*)&A[(size_t)(m0 + row) * 512 + k0 + kp];
      As[kp + 0][row] = av.x;
      As[kp + 1][row] = av.y;
      As[kp + 2][row] = av.z;
      As[kp + 3][row] = av.w;
      const int kk = tid >> 4, np = (tid & 15) << 2;
      *(float4*)&Bs[kk][np] = *(const float4*)&W[(size_t)(k0 + kk) * 512 + n0 + np];
    }
    __syncthreads();
#pragma unroll
    for (int kk = 0; kk < 16; ++kk) {
      float4 a = *(const float4*)&As[kk][ty << 2];
      float4 b = *(const float4*)&Bs[kk][tx << 2];
      c[0][0] += a.x * b.x; c[0][1] += a.x * b.y; c[0][2] += a.x * b.z; c[0][3] += a.x * b.w;
      c[1][0] += a.y * b.x; c[1][1] += a.y * b.y; c[1][2] += a.y * b.z; c[1][3] += a.y * b.w;
      c[2][0] += a.z * b.x; c[2][1] += a.z * b.y; c[2][2] += a.z * b.z; c[2][3] += a.z * b.w;
      c[3][0] += a.w * b.x; c[3][1] += a.w * b.y; c[3][2] += a.w * b.z; c[3][3] += a.w * b.w;
    }
    __syncthreads();
  }
  float4 bv = *(const float4*)&bias[n0 + (tx << 2)];
  float bvv[4] = {bv.x, bv.y, bv.z, bv.w};
  const int qlen = 1 << qsh;
  const int qmask = qlen - 1;
#pragma unroll
  for (int i = 0; i < 4; ++i) {
#pragma unroll
    for (int j = 0; j < 4; ++j) {
      float val = c[i][j] + bvv[j];
      int m = m0 + (ty << 2) + i;
      int n = n0 + (tx << 2) + j;
      int h = n >> 6, d = n & 63;
      int bb = m >> qsh, q = m & qmask;
      CT[(((size_t)bb * 8 + h) * 64 + d) * qlen + q] = val;
    }
  }
}

// ---- scores: 128(q) x 128(s) tile per block, 8x8 micro, k-major LDS ----
__global__ __launch_bounds__(256)
void score_kernel(const float* __restrict__ qT, const float* __restrict__ kT,
                  const u64* __restrict__ mbits, float* __restrict__ sbuf, int sl0) {
  __shared__ float Qs[64][128];
  __shared__ float Ks[64][128];
  const int sl = sl0 + blockIdx.z;
  const int b = sl >> 3, h = sl & 7;
  const int s0 = blockIdx.x << 7, q0 = blockIdx.y << 7;
  const int tid = threadIdx.x;
  const float* qbase = qT + (size_t)sl * 64 * 2048 + q0;
  const float* kbase = kT + (size_t)h * 64 * 4096 + s0;
  float4* Qf = (float4*)&Qs[0][0];
  float4* Kf = (float4*)&Ks[0][0];
#pragma unroll
  for (int u = 0; u < 8; ++u) {
    int i = (u << 8) + tid;
    int row = i >> 5, col = (i & 31) << 2;
    Qf[i] = *(const float4*)(qbase + (size_t)row * 2048 + col);
    Kf[i] = *(const float4*)(kbase + (size_t)row * 4096 + col);
  }
  __syncthreads();
  const int tx = tid & 15, ty = tid >> 4;
  float c[8][8] = {};
#pragma unroll 4
  for (int g = 0; g < 16; ++g) {
    const int kk = g << 2;
    float qa[8][4], kb[8][4];
#pragma unroll
    for (int t = 0; t < 4; ++t) {
#pragma unroll
      for (int i = 0; i < 8; ++i) qa[i][t] = Qs[kk + t][(ty << 3) + i];
#pragma unroll
      for (int j = 0; j < 4; ++j) {
        kb[j][t]     = Ks[kk + t][(tx << 2) + j];
        kb[4 + j][t] = Ks[kk + t][64 + (tx << 2) + j];
      }
    }
#pragma unroll
    for (int i = 0; i < 8; ++i)
#pragma unroll
      for (int j = 0; j < 8; ++j)
        c[i][j] += qa[i][0] * kb[j][0] + qa[i][1] * kb[j][1]
                 + qa[i][2] * kb[j][2] + qa[i][3] * kb[j][3];
  }
  float* srow = sbuf + ((size_t)blockIdx.z * 2048 + q0) * 4096 + s0;
  const u64* mrow = mbits + ((size_t)(b * 2048 + q0)) * 64 + (s0 >> 6);
#pragma unroll
  for (int i = 0; i < 8; ++i) {
    const int row = (ty << 3) + i;
    u64 wA = mrow[(size_t)row * 64];
    u64 wB = mrow[(size_t)row * 64 + 1];
    float4 o0, o1;
    o0.x = ((wA >> ((tx << 2) + 0)) & 1) ? c[i][0] * 0.125f : NEGV;
    o0.y = ((wA >> ((tx << 2) + 1)) & 1) ? c[i][1] * 0.125f : NEGV;
    o0.z = ((wA >> ((tx << 2) + 2)) & 1) ? c[i][2] * 0.125f : NEGV;
    o0.w = ((wA >> ((tx << 2) + 3)) & 1) ? c[i][3] * 0.125f : NEGV;
    o1.x = ((wB >> ((tx << 2) + 0)) & 1) ? c[i][4] * 0.125f : NEGV;
    o1.y = ((wB >> ((tx << 2) + 1)) & 1) ? c[i][5] * 0.125f : NEGV;
    o1.z = ((wB >> ((tx << 2) + 2)) & 1) ? c[i][6] * 0.125f : NEGV;
    o1.w = ((wB >> ((tx << 2) + 3)) & 1) ? c[i][7] * 0.125f : NEGV;
    *(float4*)&srow[(size_t)row * 4096 + (tx << 2)] = o0;
    *(float4*)&srow[(size_t)row * 4096 + 64 + (tx << 2)] = o1;
  }
}

// ---- select v3: one wave per q-row, candidate compaction + register search ----
__global__ __launch_bounds__(256)
void select_kernel(const float* __restrict__ sbuf, const float* __restrict__ vbuf,
                   float* __restrict__ ctxbuf, int sl0) {
  const int sl = sl0 + blockIdx.y;
  const int b = sl >> 3, h = sl & 7;
  const int w = threadIdx.x >> 6, lane = threadIdx.x & 63;
  const int qi = (blockIdx.x << 2) + w;
  __shared__ u32  cv_lds[4][NCAND][64];   // candidate ord values, [slot][lane]
  __shared__ int  ci_lds[4][NCAND][64];   // candidate row indices
  __shared__ int   s_idx[4][MAXSEL];
  __shared__ float s_e[4][MAXSEL];

  const float* srow = sbuf + ((size_t)blockIdx.y * 2048 + qi) * 4096;
  const u32 ordneg = f2ord(NEGV);
  const u64 lmask_lt = (1ull << lane) - 1ull;

  u32 u[64];
#pragma unroll
  for (int j = 0; j < 16; ++j) {
    float4 v = *(const float4*)(srow + (j << 8) + (lane << 2));
    u[j * 4 + 0] = f2ord(v.x);
    u[j * 4 + 1] = f2ord(v.y);
    u[j * 4 + 2] = f2ord(v.z);
    u[j * 4 + 3] = f2ord(v.w);
  }
  // per-lane max -> wave max (fm) and wave min-of-lane-maxes (lo0)
  u32 lmax = 0;
#pragma unroll
  for (int e = 0; e < 64; ++e) lmax = u[e] > lmax ? u[e] : lmax;
  u32 mx = lmax, mn = lmax;
#pragma unroll
  for (int off = 32; off; off >>= 1) {
    u32 a = (u32)__shfl_xor((int)mx, off, 64);
    u32 bq = (u32)__shfl_xor((int)mn, off, 64);
    mx = a > mx ? a : mx;
    mn = bq < mn ? bq : mn;
  }
  const float fm = ord2f(mx);
  const u32 lo0 = mn;

  // compact candidates (>= lo0) into LDS slots [slot][lane]
  int cnt = 0;
#pragma unroll
  for (int e = 0; e < 64; ++e) {
    u32 ue = u[e];
    if (ue >= lo0 && ue != ordneg) {
      if (cnt < NCAND) {
        cv_lds[w][cnt][lane] = ue;
        ci_lds[w][cnt][lane] = ((e >> 2) << 8) + (lane << 2) + (e & 3);
      }
      cnt++;
    }
  }
  const bool fallback = (__ballot(cnt > NCAND) != 0ull);

  u32 thr;
  int nsel;          // survivor count (wave-uniform)
  float esum = 0.f;  // per-lane partial, reduced below

  if (!fallback) {
    asm volatile("s_waitcnt lgkmcnt(0)" ::: "memory");
    u32 cv[NCAND];
    int ci[NCAND];
#pragma unroll
    for (int j = 0; j < NCAND; ++j) {
      u32 raw = cv_lds[w][j][lane];
      cv[j] = (j < cnt) ? raw : 0u;
      ci[j] = ci_lds[w][j][lane];
    }
    // binary search on [lo0, mx] over register candidates
    u32 lo = lo0, hi = mx + 1;
    while (hi - lo > 1) {
      u32 mid = lo + ((hi - lo) >> 1);
      int c2 = 0;
#pragma unroll
      for (int j = 0; j < NCAND; ++j)
        c2 += __popcll(__ballot(cv[j] >= mid));
      if (c2 >= 64) lo = mid; else hi = mid;
    }
    thr = lo;
    // ballot-prefix survivor append (deterministic, no atomics)
    int base = 0;
#pragma unroll
    for (int j = 0; j < NCAND; ++j) {
      bool pred = (j < cnt) && (cv[j] >= thr);
      u64 m = __ballot(pred);
      int ofs = base + __popcll(m & lmask_lt);
      if (pred && ofs < MAXSEL) {
        float ev = __expf(ord2f(cv[j]) - fm);
        s_idx[w][ofs] = ci[j];
        s_e[w][ofs] = ev;
        esum += ev;
      }
      base += (int)__popcll(m);
    }
    nsel = base < MAXSEL ? base : MAXSEL;
  } else {
    // rare: full binary search over all 64 elements
    u32 lo = ordneg, hi = mx + 1;
    while (hi - lo > 1) {
      u32 mid = lo + ((hi - lo) >> 1);
      int c2 = 0;
#pragma unroll
      for (int e = 0; e < 64; ++e)
        c2 += __popcll(__ballot(u[e] >= mid));
      if (c2 >= 64) lo = mid; else hi = mid;
    }
    thr = lo;
    int base = 0;
#pragma unroll
    for (int e = 0; e < 64; ++e) {
      bool pred = (u[e] >= thr) && (u[e] != ordneg);
      u64 m = __ballot(pred);
      int ofs = base + __popcll(m & lmask_lt);
      if (pred && ofs < MAXSEL) {
        float ev = __expf(ord2f(u[e]) - fm);
        s_idx[w][ofs] = ((e >> 2) << 8) + (lane << 2) + (e & 3);
        s_e[w][ofs] = ev;
        esum += ev;
      }
      base += (int)__popcll(m);
    }
    nsel = base < MAXSEL ? base : MAXSEL;
  }

#pragma unroll
  for (int off = 32; off; off >>= 1) esum += __shfl_xor(esum, off, 64);
  const float rs = 1.0f / esum;
  asm volatile("s_waitcnt lgkmcnt(0)" ::: "memory");

  float acc = 0.f;
  const float* vb = vbuf + h * 64 + lane;
#pragma unroll 4
  for (int j = 0; j < nsel; ++j)
    acc += s_e[w][j] * vb[(size_t)s_idx[w][j] << 9];
  ctxbuf[((size_t)(b * 2048 + qi)) * 512 + h * 64 + lane] = acc * rs;
}

extern "C" void kernel_launch(void* const* d_in, const int* in_sizes, int n_in,
                              void* d_out, int out_size, void* d_ws, size_t ws_size,
                              hipStream_t stream) {
  const float* main_in = (const float*)d_in[0];
  const float* side_in = (const float*)d_in[1];
  const int*   mask    = (const int*)d_in[2];
  const float* Wq = (const float*)d_in[3];
  const float* bq = (const float*)d_in[4];
  const float* Wk = (const float*)d_in[5];
  const float* bk = (const float*)d_in[6];
  const float* Wv = (const float*)d_in[7];
  const float* bv = (const float*)d_in[8];
  const float* Wo = (const float*)d_in[9];
  const float* bo = (const float*)d_in[10];
  float* out = (float*)d_out;

  char* ws = (char*)d_ws;
  float* qT   = (float*)(ws);                       // 8 MB  [16][64][2048]
  float* kT   = (float*)(ws + ((size_t)8 << 20));   // 8 MB  [8][64][4096]
  float* vbuf = (float*)(ws + ((size_t)16 << 20));  // 8 MB  [4096][512]
  float* ctxb = (float*)(ws + ((size_t)24 << 20));  // 8 MB  [4096][512]
  u64* mbits  = (u64*)(ws + ((size_t)32 << 20));    // 2 MB  [2][2048][64]
  float* sbuf = (float*)(ws + ((size_t)34 << 20));  // nz * 32 MB
  const size_t base = (size_t)34 << 20;
  const size_t sliceb = (size_t)2048 * 4096 * 4;

  int nz = 1;
  if (ws_size > base + sliceb) {
    size_t m = (ws_size - base) / sliceb;
    nz = (int)(m > 16 ? 16 : m);
  }

  pack_mask<<<1024, 256, 0, stream>>>(mask, mbits);
  gemm_bias_T<<<dim3(8, 64), 256, 0, stream>>>(main_in, Wq, bq, qT, 11);
  gemm_bias_T<<<dim3(8, 64), 256, 0, stream>>>(side_in, Wk, bk, kT, 12);
  gemm_bias  <<<dim3(8, 64), 256, 0, stream>>>(side_in, Wv, bv, vbuf);

  for (int sl0 = 0; sl0 < 16; sl0 += nz) {
    int z = nz < (16 - sl0) ? nz : (16 - sl0);
    score_kernel <<<dim3(32, 16, z), 256, 0, stream>>>(qT, kT, mbits, sbuf, sl0);
    select_kernel<<<dim3(512, z), 256, 0, stream>>>(sbuf, vbuf, ctxb, sl0);
  }

  gemm_bias<<<dim3(8, 64), 256, 0, stream>>>(ctxb, Wo, bo, out);
}